// Round 7
// baseline (138.670 us; speedup 1.0000x reference)
//
#include <hip/hip_runtime.h>

#define E_TOTAL 800000
#define NN      50000
#define ND      64
#define ED      32
#define HD      128
#define OD      64
#define IND     160      // ED + 2*ND
#define MT2     256      // edges per block = 2 tiles of 128
#define NTHREADS 512

typedef __attribute__((ext_vector_type(8))) short          short8;
typedef __attribute__((ext_vector_type(4))) float          f32x4;
typedef __attribute__((ext_vector_type(8))) unsigned short u16x8;
typedef __attribute__((ext_vector_type(4))) unsigned short u16x4;

__device__ __forceinline__ unsigned short f2bf(float f) {
  union { float f; unsigned u; } v; v.f = f;
  unsigned r = v.u + 0x7fffu + ((v.u >> 16) & 1u);   // RNE
  return (unsigned short)(r >> 16);
}

// LDS: H (32 frags, wave-private: wave w owns frags [w*4, w*4+4), reused for
// both tiles) + W1 (40 frags). frag = 1024B; lane l's 16B at frag*1024 + l*16
// -> conflict-free b128 ops.
#define H_FRAGS  32
#define SMEM_U16 ((H_FRAGS + 40) * 512)     // 36864 u16
#define SMEM_BYTES (SMEM_U16 * 2)           // 73728 B -> 2 blocks/CU

// ---------- prepass: f32 -> bf16 node table ----------
__global__ void cvt_nodes(const float* __restrict__ in, unsigned short* __restrict__ out, int n4) {
  int i = blockIdx.x * blockDim.x + threadIdx.x;
  const int stride = gridDim.x * blockDim.x;
  for (; i < n4; i += stride) {
    float4 v = ((const float4*)in)[i];
    u16x4 o = { f2bf(v.x), f2bf(v.y), f2bf(v.z), f2bf(v.w) };
    ((u16x4*)out)[i] = o;
  }
}

// ---------- prepass: pack W1 into B-fragment order ----------
__global__ void pack_w1(const float* __restrict__ w, unsigned short* __restrict__ out) {
  int i = blockIdx.x * blockDim.x + threadIdx.x;
  if (i >= HD * IND) return;
  int j = i & 7, l = (i >> 3) & 63, f = i >> 9;   // f in [0,40)
  int ks = f >> 3, t = f & 7;
  int k = ks * 32 + (l >> 4) * 8 + j;
  int n = t * 16 + (l & 15);
  out[i] = f2bf(w[k * HD + n]);
}

// ---------- prepass: pack W2 into B-fragment order ----------
__global__ void pack_w2(const float* __restrict__ w, unsigned short* __restrict__ out) {
  int i = blockIdx.x * blockDim.x + threadIdx.x;
  if (i >= OD * HD) return;
  int j = i & 7, l = (i >> 3) & 63, f = i >> 9;   // f in [0,16)
  int ks = f >> 2, t = f & 3;
  int k = ks * 32 + (l >> 4) * 8 + j;
  int n = t * 16 + (l & 15);
  out[i] = f2bf(w[k * OD + n]);
}

// ---------- main fused kernel: two 128-edge tiles per block ----------
__global__ __launch_bounds__(NTHREADS, 4)
void edge_mlp(const int* __restrict__ eidx,
              const float* __restrict__ ef,
              const unsigned short* __restrict__ nbf,
              const unsigned short* __restrict__ w1p,
              const unsigned short* __restrict__ w2p,
              const float* __restrict__ b1,
              const float* __restrict__ b2,
              float* __restrict__ out)
{
  extern __shared__ unsigned short sm[];
  unsigned short* Hs = sm;                  // 32 frags, wave-private slices
  unsigned short* W1 = sm + H_FRAGS * 512;  // 40 frags

  const int tid  = threadIdx.x;
  const int wid  = tid >> 6;
  const int lane = tid & 63;
  const int lq   = lane >> 4;
  const int lr   = lane & 15;
  const long eA  = (long)blockIdx.x * MT2 + wid * 16 + lr;  // tile-A edge row
  const long eB  = eA + 128;                                 // tile-B edge row

  // ---- 1) index loads first: head of the dependent chain (4 loads)
  int siA = eidx[eA];
  int tiA = eidx[E_TOTAL + eA];
  int siB = eidx[eB];
  int tiB = eidx[E_TOTAL + eB];

  // ---- 2) edge features for both tiles (independent, in flight early)
  const float4 evA0 = *(const float4*)(ef + eA * ED + lq * 8);
  const float4 evA1 = *(const float4*)(ef + eA * ED + lq * 8 + 4);
  const float4 evB0 = *(const float4*)(ef + eB * ED + lq * 8);
  const float4 evB1 = *(const float4*)(ef + eB * ED + lq * 8 + 4);

  // ---- 3) W1 chunk loads (independent, linear, coalesced)
  u16x8 wv[5];
  #pragma unroll
  for (int c = 0; c < 5; ++c)
    wv[c] = *(const u16x8*)(w1p + (tid + c * NTHREADS) * 8);

  // ---- 4) biases (L1-broadcast)
  float b1v[8];
  #pragma unroll
  for (int t = 0; t < 8; ++t) b1v[t] = b1[t * 16 + lr];
  float b2v[4];
  #pragma unroll
  for (int t = 0; t < 4; ++t) b2v[t] = b2[t * 16 + lr];

  // ---- 5) node-row gathers for BOTH tiles straight into A-frag registers
  siA = siA < 0 ? 0 : (siA >= NN ? NN - 1 : siA);
  tiA = tiA < 0 ? 0 : (tiA >= NN ? NN - 1 : tiA);
  siB = siB < 0 ? 0 : (siB >= NN ? NN - 1 : siB);
  tiB = tiB < 0 ? 0 : (tiB >= NN ? NN - 1 : tiB);
  const unsigned short* srA = nbf + (long)siA * ND;
  const unsigned short* trA = nbf + (long)tiA * ND;
  const unsigned short* srB = nbf + (long)siB * ND;
  const unsigned short* trB = nbf + (long)tiB * ND;
  const short8 gA0 = *(const short8*)(srA + lq * 8);
  const short8 gA1 = *(const short8*)(srA + 32 + lq * 8);
  const short8 gA2 = *(const short8*)(trA + lq * 8);
  const short8 gA3 = *(const short8*)(trA + 32 + lq * 8);
  const short8 gB0 = *(const short8*)(srB + lq * 8);
  const short8 gB1 = *(const short8*)(srB + 32 + lq * 8);
  const short8 gB2 = *(const short8*)(trB + lq * 8);
  const short8 gB3 = *(const short8*)(trB + 32 + lq * 8);

  // ---- 6) W1 -> LDS (conflict-free b128)
  #pragma unroll
  for (int c = 0; c < 5; ++c)
    *(u16x8*)(W1 + (tid + c * NTHREADS) * 8) = wv[c];

  // ---- 7) scheduling wall: loads above may NOT sink below this point;
  //         compute below may not hoist above. Issue order is now pinned,
  //         but vmcnt waits still land at first USE (no drain here).
  __builtin_amdgcn_sched_barrier(0);

  // ---- 8) the ONLY barrier: W1 visible. lgkm-only wait — gathers in flight.
  asm volatile("s_waitcnt lgkmcnt(0)" ::: "memory");
  __builtin_amdgcn_s_barrier();

  #define L1STEP(AV, KS, ACC)                                                   \
    _Pragma("unroll")                                                           \
    for (int t = 0; t < 8; ++t) {                                               \
      const short8 b = *(const short8*)(W1 + ((KS) * 8 + t) * 512 + lane * 8);  \
      ACC[t] = __builtin_amdgcn_mfma_f32_16x16x32_bf16(AV, b, ACC[t], 0, 0, 0); \
    }

  #define COMPUTE(G0, G1, G2, G3, EV0, EV1, MB)                                 \
    {                                                                           \
      f32x4 acc[8];                                                             \
      _Pragma("unroll")                                                         \
      for (int t = 0; t < 8; ++t) acc[t] = (f32x4)0.0f;                         \
      L1STEP(G0, 1, acc)                                                        \
      L1STEP(G1, 2, acc)                                                        \
      L1STEP(G2, 3, acc)                                                        \
      L1STEP(G3, 4, acc)                                                        \
      short8 aef;                                                               \
      aef[0] = (short)f2bf(EV0.x); aef[1] = (short)f2bf(EV0.y);                 \
      aef[2] = (short)f2bf(EV0.z); aef[3] = (short)f2bf(EV0.w);                 \
      aef[4] = (short)f2bf(EV1.x); aef[5] = (short)f2bf(EV1.y);                 \
      aef[6] = (short)f2bf(EV1.z); aef[7] = (short)f2bf(EV1.w);                 \
      L1STEP(aef, 0, acc)                                                       \
      _Pragma("unroll")                                                         \
      for (int t = 0; t < 8; ++t) {                                             \
        _Pragma("unroll")                                                       \
        for (int r = 0; r < 4; ++r) {                                           \
          float h = acc[t][r] + b1v[t];                                         \
          h = h > 0.0f ? h : 0.0f;                                              \
          const int k    = t * 16 + lr;                                         \
          const int frag = wid * 4 + (k >> 5);                                  \
          const int l2   = (((k >> 3) & 3) << 4) + lq * 4 + r;                  \
          Hs[frag * 512 + l2 * 8 + (k & 7)] = f2bf(h);                          \
        }                                                                       \
      }                                                                         \
      short8 a2[4];                                                             \
      _Pragma("unroll")                                                         \
      for (int ks = 0; ks < 4; ++ks)                                            \
        a2[ks] = *(const short8*)(Hs + (wid * 4 + ks) * 512 + lane * 8);        \
      f32x4 acc2[4];                                                            \
      _Pragma("unroll")                                                         \
      for (int t = 0; t < 4; ++t) acc2[t] = (f32x4)0.0f;                        \
      _Pragma("unroll")                                                         \
      for (int t = 0; t < 4; ++t) {                                             \
        _Pragma("unroll")                                                       \
        for (int ks = 0; ks < 4; ++ks) {                                        \
          const short8 b = *(const short8*)(w2p + ((ks * 4 + t) * 64 + lane) * 8); \
          acc2[t] = __builtin_amdgcn_mfma_f32_16x16x32_bf16(a2[ks], b, acc2[t], 0, 0, 0); \
        }                                                                       \
      }                                                                         \
      const long mbase = (MB) + wid * 16 + lq * 4;                              \
      _Pragma("unroll")                                                         \
      for (int t = 0; t < 4; ++t) {                                             \
        _Pragma("unroll")                                                       \
        for (int r = 0; r < 4; ++r) {                                           \
          out[(mbase + r) * OD + t * 16 + lr] = acc2[t][r] + b2v[t];            \
        }                                                                       \
      }                                                                         \
    }

  // ---- tile A: its gather wait lands here; tile B's stay in flight
  COMPUTE(gA0, gA1, gA2, gA3, evA0, evA1, (long)blockIdx.x * MT2)
  // ---- tile B: gathers completed under tile A's compute
  COMPUTE(gB0, gB1, gB2, gB3, evB0, evB1, (long)blockIdx.x * MT2 + 128)

  #undef COMPUTE
  #undef L1STEP
}

extern "C" void kernel_launch(void* const* d_in, const int* in_sizes, int n_in,
                              void* d_out, int out_size, void* d_ws, size_t ws_size,
                              hipStream_t stream) {
  const int*   eidx = (const int*)d_in[0];      // (2, E) int32
  const float* nf   = (const float*)d_in[1];    // (NN, 64)
  const float* ef   = (const float*)d_in[2];    // (E, 32)
  const float* w1   = (const float*)d_in[3];    // (160, 128)
  const float* b1   = (const float*)d_in[4];    // (128,)
  const float* w2   = (const float*)d_in[5];    // (128, 64)
  const float* b2   = (const float*)d_in[6];    // (64,)
  float*       out  = (float*)d_out;            // (E, 64)

  unsigned short* nbf = (unsigned short*)d_ws;            // NN*ND
  unsigned short* w1p = nbf + (long)NN * ND;              // HD*IND
  unsigned short* w2p = w1p + (long)HD * IND;             // OD*HD

  cvt_nodes<<<1024, 256, 0, stream>>>(nf, nbf, (NN * ND) / 4);
  pack_w1<<<(HD * IND + 255) / 256, 256, 0, stream>>>(w1, w1p);
  pack_w2<<<(OD * HD + 255) / 256, 256, 0, stream>>>(w2, w2p);

  hipFuncSetAttribute((const void*)edge_mlp,
                      hipFuncAttributeMaxDynamicSharedMemorySize, SMEM_BYTES);
  edge_mlp<<<E_TOTAL / MT2, NTHREADS, SMEM_BYTES, stream>>>(
      eidx, ef, nbf, w1p, w2p, b1, b2, out);
}